// Round 1
// 562.858 us; speedup vs baseline: 1.0856x; 1.0856x over previous
//
#include <hip/hip_runtime.h>

// LiquidLoRA (fp32 I/O): out[s,o] = 2 * sum_r (sum_i x[s,i]*A[r,i]) * Beff[o,r]
// Kernel A: liquid dynamics in fp32 VALU -> Beff bf16 in d_ws; also pre-converts
//           lora_A -> bf16 (abf) so the GEMM hot loop does no A conversions.
// Kernel B: fused skinny GEMM chain, bf16 MFMA, fp32 loads/stores.
//   v2: M_blk 64->32 (grid 512 = 2 blocks/CU, occupancy 23->~47%) +
//       register-prefetch software pipeline in both phases (next tile's global
//       loads issued one iteration ahead of use). LDS 70.6 KB -> 44.5 KB.
// Roofline: 536 MB HBM (x + out) -> ~85 us floor at 6.3 TB/s.

typedef __attribute__((ext_vector_type(8))) short short8;
typedef __attribute__((ext_vector_type(4))) short short4_t;
typedef __attribute__((ext_vector_type(4))) float f32x4;

static __device__ __forceinline__ unsigned short f2bf(float f) {
    unsigned int x;
    __builtin_memcpy(&x, &f, 4);
    x += 0x7fffu + ((x >> 16) & 1);   // round-to-nearest-even
    return (unsigned short)(x >> 16);
}
static __device__ __forceinline__ float bf2f(unsigned short u) {
    unsigned int x = ((unsigned int)u) << 16;
    float f;
    __builtin_memcpy(&f, &x, 4);
    return f;
}

// ---------------- Kernel A: liquid dynamics (fp32) -> Beff [4096][64] bf16 ----
// grid 256 x block 256. Block = 16 O-rows; thread (row, cg) owns 4 cols.
// Preamble: each thread also converts 4 elements of lora_A -> abf (bf16).
__global__ __launch_bounds__(256) void liquid_kernel(
    const float* __restrict__ loraB,    // [4096][64]
    const float* __restrict__ hiddenB,  // [4096][64]
    const float* __restrict__ Wg,       // [64][128]
    const float* __restrict__ bg,       // [64]
    const float* __restrict__ Wt,       // [64][128]
    const float* __restrict__ bt,       // [64]
    const float* __restrict__ loraA,    // [64][4096]
    unsigned short* __restrict__ beff,  // [4096][64] bf16
    unsigned short* __restrict__ abf)   // [64][4096] bf16
{
    // ---- A -> bf16 (262144 elems = 256 blocks * 256 threads * 4) ----
    {
        const int idx = (blockIdx.x * 256 + threadIdx.x) * 4;
        f32x4 a = *(const f32x4*)&loraA[idx];
        short4_t ab;
#pragma unroll
        for (int j = 0; j < 4; ++j) ab[j] = (short)f2bf(a[j]);
        *(short4_t*)&abf[idx] = ab;
    }

    __shared__ __align__(16) float inp[16][132];   // [target(64) | h(64)], pad
    const int tid = threadIdx.x;
    const int row = tid >> 4;       // 0..15
    const int cg  = tid & 15;       // 0..15
    const int orow = blockIdx.x * 16 + row;
    const int c0 = cg * 4;

    float tgt[4], h[4], bgv[4], btv[4];
#pragma unroll
    for (int i = 0; i < 4; ++i) {
        tgt[i] = loraB[orow * 64 + c0 + i];
        h[i]   = hiddenB[orow * 64 + c0 + i];
        bgv[i] = bg[c0 + i];
        btv[i] = bt[c0 + i];
        inp[row][c0 + i] = tgt[i];     // target half, written once
    }
    for (int step = 0; step < 3; ++step) {
#pragma unroll
        for (int i = 0; i < 4; ++i) inp[row][64 + c0 + i] = h[i];
        __syncthreads();
        float dg[4], dt_[4];
#pragma unroll
        for (int c = 0; c < 4; ++c) { dg[c] = bgv[c]; dt_[c] = btv[c]; }
        for (int k = 0; k < 128; k += 4) {
            f32x4 iv = *(f32x4*)&inp[row][k];
#pragma unroll
            for (int c = 0; c < 4; ++c) {
                f32x4 wgv = *(const f32x4*)&Wg[(c0 + c) * 128 + k];
                f32x4 wtv = *(const f32x4*)&Wt[(c0 + c) * 128 + k];
                dg[c]  += iv[0]*wgv[0] + iv[1]*wgv[1] + iv[2]*wgv[2] + iv[3]*wgv[3];
                dt_[c] += iv[0]*wtv[0] + iv[1]*wtv[1] + iv[2]*wtv[2] + iv[3]*wtv[3];
            }
        }
#pragma unroll
        for (int c = 0; c < 4; ++c) {
            float f   = 1.f / (1.f + __expf(-dg[c]));
            float tau = 0.1f + 9.9f / (1.f + __expf(-dt_[c]));
            float a   = 1.f / tau + f;
            float dec = __expf(-a * 0.1f);
            h[c] = h[c] * dec + (f / a) * tgt[c] * (1.f - dec);
        }
        __syncthreads();   // h-half writes of next step wait for all dot reads
    }
#pragma unroll
    for (int i = 0; i < 4; ++i)
        beff[orow * 64 + c0 + i] = f2bf(h[i]);
}

// ---------------- Kernel B: out = 2 * (x @ A^T) @ Beff^T ----------------
// grid 512 x block 512 (8 waves), M_blk=32 -> 2 blocks/CU.
// Phase 1: t[32x64] = x_blk @ A^T (BK=128, prefetched; A already bf16).
// Phase 2: O in 128-col chunks; 2x MFMA (hi,lo); fp32 bounce; float4 stores.
__global__ __launch_bounds__(512, 4) void lora_gemm_kernel(
    const float* __restrict__ x,             // [16384][4096]
    const unsigned short* __restrict__ abf,  // [64][4096] bf16
    const unsigned short* __restrict__ beff, // [4096][64] bf16
    float* __restrict__ out)                 // [16384][4096]
{
    __shared__ __align__(16) union {
        struct { unsigned short xs[32 * 136]; unsigned short as[64 * 136]; } p1;
        struct { unsigned short bs[128 * 72]; float bounce[32 * 132]; } p2;
    } sm;
    __shared__ __align__(16) unsigned short tsh[32 * 72];
    __shared__ __align__(16) unsigned short tsl[32 * 72];

    const int tid  = threadIdx.x;
    const int lane = tid & 63;
    const int w    = tid >> 6;
    const int q    = lane >> 4;
    const int ln   = lane & 15;
    const int m0   = blockIdx.x * 32;
    const int ms   = (w >> 2) * 16;   // m-strip (block-local): 0 or 16
    const int nc   = (w & 3) * 16;    // phase-1 n-chunk: 0/16/32/48

    // per-thread staging coords (constant across iterations)
    const int xr0 = tid >> 5,        xc0 = (tid & 31) * 4;   // x rows 0..15
    const int xr1 = xr0 + 16;                                // x rows 16..31
    const int ar0 = tid >> 4,        ac0 = (tid & 15) * 8;   // A rows 0..31
    const int ar1 = ar0 + 32;                                // A rows 32..63
    const int br0 = tid >> 3,        bc0 = (tid & 7) * 8;    // beff rows 0..63
    const int br1 = br0 + 64;                                // beff rows 64..127

    f32x4 acc = (f32x4){0.f, 0.f, 0.f, 0.f};

    // ---- phase 1: t = x_blk @ A^T, register-prefetch pipeline ----
    const float* xp0 = &x[(size_t)(m0 + xr0) * 4096 + xc0];
    const float* xp1 = &x[(size_t)(m0 + xr1) * 4096 + xc0];
    const unsigned short* ap0 = &abf[(size_t)ar0 * 4096 + ac0];
    const unsigned short* ap1 = &abf[(size_t)ar1 * 4096 + ac0];

    f32x4 xcur[2]; short8 acur[2];
    xcur[0] = *(const f32x4*)xp0;
    xcur[1] = *(const f32x4*)xp1;
    acur[0] = *(const short8*)ap0;
    acur[1] = *(const short8*)ap1;

    for (int it = 0; it < 32; ++it) {
        f32x4 xn[2]; short8 an[2];
        if (it < 31) {                      // issue next tile's loads NOW
            const int k = (it + 1) * 128;
            xn[0] = *(const f32x4*)(xp0 + k);
            xn[1] = *(const f32x4*)(xp1 + k);
            an[0] = *(const short8*)(ap0 + k);
            an[1] = *(const short8*)(ap1 + k);
        }
        __syncthreads();                    // prev iter's LDS reads done
        {
            short4_t xb0, xb1;
#pragma unroll
            for (int j = 0; j < 4; ++j) {
                xb0[j] = (short)f2bf(xcur[0][j]);
                xb1[j] = (short)f2bf(xcur[1][j]);
            }
            *(short4_t*)&sm.p1.xs[xr0 * 136 + xc0] = xb0;
            *(short4_t*)&sm.p1.xs[xr1 * 136 + xc0] = xb1;
            *(short8*)&sm.p1.as[ar0 * 136 + ac0] = acur[0];
            *(short8*)&sm.p1.as[ar1 * 136 + ac0] = acur[1];
        }
        __syncthreads();
#pragma unroll
        for (int kk = 0; kk < 128; kk += 32) {
            short8 af  = *(short8*)&sm.p1.xs[(ms + ln) * 136 + kk + q * 8];
            short8 bfv = *(short8*)&sm.p1.as[(nc + ln) * 136 + kk + q * 8];
            acc = __builtin_amdgcn_mfma_f32_16x16x32_bf16(af, bfv, acc, 0, 0, 0);
        }
        if (it < 31) {
            xcur[0] = xn[0]; xcur[1] = xn[1];
            acur[0] = an[0]; acur[1] = an[1];
        }
    }
    // park t as hi+lo bf16 (error ~2^-16); wave-private writes, synced below
#pragma unroll
    for (int r = 0; r < 4; ++r) {
        float v = acc[r];
        unsigned short hh = f2bf(v);
        tsh[(ms + q * 4 + r) * 72 + nc + ln] = hh;
        tsl[(ms + q * 4 + r) * 72 + nc + ln] = f2bf(v - bf2f(hh));
    }

    // ---- phase 2: out_blk = 2 * t @ Beff^T, prefetched beff chunks ----
    const int oc = (w & 3) * 32;
    const unsigned short* bp0 = &beff[(size_t)br0 * 64 + bc0];
    const unsigned short* bp1 = &beff[(size_t)br1 * 64 + bc0];
    short8 bcur[2];
    bcur[0] = *(const short8*)bp0;
    bcur[1] = *(const short8*)bp1;

    for (int it = 0; it < 32; ++it) {
        const int o0 = it * 128;
        short8 bn[2];
        if (it < 31) {                      // next 128x64 beff chunk (L2)
            bn[0] = *(const short8*)(bp0 + (it + 1) * 8192);
            bn[1] = *(const short8*)(bp1 + (it + 1) * 8192);
        }
        __syncthreads();   // iter0: ts writes + p1 LDS reads done; else bounce/bs reads done
        *(short8*)&sm.p2.bs[br0 * 72 + bc0] = bcur[0];
        *(short8*)&sm.p2.bs[br1 * 72 + bc0] = bcur[1];
        __syncthreads();
        f32x4 a2[2];
        a2[0] = (f32x4){0.f, 0.f, 0.f, 0.f};
        a2[1] = (f32x4){0.f, 0.f, 0.f, 0.f};
#pragma unroll
        for (int kk = 0; kk < 64; kk += 32) {
            short8 ah = *(short8*)&tsh[(ms + ln) * 72 + kk + q * 8];
            short8 al = *(short8*)&tsl[(ms + ln) * 72 + kk + q * 8];
#pragma unroll
            for (int t = 0; t < 2; ++t) {
                short8 bfv = *(short8*)&sm.p2.bs[(oc + t * 16 + ln) * 72 + kk + q * 8];
                a2[t] = __builtin_amdgcn_mfma_f32_16x16x32_bf16(ah, bfv, a2[t], 0, 0, 0);
                a2[t] = __builtin_amdgcn_mfma_f32_16x16x32_bf16(al, bfv, a2[t], 0, 0, 0);
            }
        }
#pragma unroll
        for (int t = 0; t < 2; ++t)
#pragma unroll
            for (int r = 0; r < 4; ++r)
                sm.p2.bounce[(ms + q * 4 + r) * 132 + oc + t * 16 + ln] =
                    a2[t][r] * 2.0f;
        __syncthreads();
        *(f32x4*)&out[(size_t)(m0 + xr0) * 4096 + o0 + xc0] =
            *(f32x4*)&sm.p2.bounce[xr0 * 132 + xc0];
        *(f32x4*)&out[(size_t)(m0 + xr1) * 4096 + o0 + xc0] =
            *(f32x4*)&sm.p2.bounce[xr1 * 132 + xc0];
        if (it < 31) { bcur[0] = bn[0]; bcur[1] = bn[1]; }
    }
}

extern "C" void kernel_launch(void* const* d_in, const int* in_sizes, int n_in,
                              void* d_out, int out_size, void* d_ws, size_t ws_size,
                              hipStream_t stream) {
    const float* x       = (const float*)d_in[0];
    const float* loraA   = (const float*)d_in[1];
    const float* loraB   = (const float*)d_in[2];
    const float* hiddenB = (const float*)d_in[3];
    const float* Wg      = (const float*)d_in[4];
    const float* bg      = (const float*)d_in[5];
    const float* Wt      = (const float*)d_in[6];
    const float* bt      = (const float*)d_in[7];
    float* out = (float*)d_out;
    unsigned short* beff = (unsigned short*)d_ws;      // 4096*64 bf16 = 512 KB
    unsigned short* abf  = beff + 4096 * 64;           // 64*4096 bf16 = 512 KB

    hipLaunchKernelGGL(liquid_kernel, dim3(256), dim3(256), 0, stream,
                       loraB, hiddenB, Wg, bg, Wt, bt, loraA, beff, abf);
    hipLaunchKernelGGL(lora_gemm_kernel, dim3(512), dim3(512), 0, stream,
                       x, abf, beff, out);
}